// Round 7
// baseline (388.655 us; speedup 1.0000x reference)
//
#include <hip/hip_runtime.h>
#include <hip/hip_bf16.h>
#include <stdint.h>

#define B_ROWS 16384
#define IN_DIM 2048
#define OUT_DIM 2048

typedef __attribute__((ext_vector_type(4))) float f32x4;
typedef __attribute__((ext_vector_type(8))) short s16x8;
typedef __attribute__((ext_vector_type(4))) unsigned short u16x4;

__device__ __forceinline__ unsigned short f2bf_rne(float f) {
  union { float f; unsigned u; } c; c.f = f;
  unsigned u = c.u;
  return (unsigned short)((u + 0x7FFFu + ((u >> 16) & 1u)) >> 16);
}

// Prep (measured NEUTRAL vs old strided version in R6 A/B: residual identical
// -> prep is at its floor; kept in the contiguous form).
#define PREP_X_BLOCKS 4096
#define PREP_W_BLOCKS 2048

__global__ void __launch_bounds__(256) prep_kernel(const float* __restrict__ x,
                                                   unsigned short* __restrict__ xn,
                                                   float* __restrict__ scale,
                                                   const float* __restrict__ W,
                                                   unsigned short* __restrict__ Wb) {
  if (blockIdx.x < PREP_X_BLOCKS) {
    const int row  = (blockIdx.x * 256 + threadIdx.x) >> 6;
    const int lane = threadIdx.x & 63;
    const f32x4* xr = (const f32x4*)(x + (size_t)row * IN_DIM);
    u16x4* xw = (u16x4*)(xn + (size_t)row * IN_DIM);

    float ss = 0.0f;
    #pragma unroll
    for (int j = 0; j < 8; ++j) {
      const int i = j * 64 + lane;          // contiguous float4 across lanes
      f32x4 v = xr[i];
      ss = fmaf(v[0], v[0], ss);
      ss = fmaf(v[1], v[1], ss);
      ss = fmaf(v[2], v[2], ss);
      ss = fmaf(v[3], v[3], ss);
      u16x4 p;
      p[0] = f2bf_rne(v[0]); p[1] = f2bf_rne(v[1]);
      p[2] = f2bf_rne(v[2]); p[3] = f2bf_rne(v[3]);
      xw[i] = p;
    }

    #pragma unroll
    for (int m = 32; m > 0; m >>= 1) ss += __shfl_xor(ss, m, 64);
    if (lane == 0) scale[row] = 1.0f / (sqrtf(ss) + 1e-4f);
  } else {
    const int base = (blockIdx.x - PREP_X_BLOCKS) * 512 + threadIdx.x;
    const f32x4* wr = (const f32x4*)W;
    u16x4* ww = (u16x4*)Wb;
    #pragma unroll
    for (int j = 0; j < 2; ++j) {
      const int i = base + j * 256;
      f32x4 v = wr[i];
      u16x4 p;
      p[0] = f2bf_rne(v[0]); p[1] = f2bf_rne(v[1]);
      p[2] = f2bf_rne(v[2]); p[3] = f2bf_rne(v[3]);
      ww[i] = p;
    }
  }
}

// ===========================================================================
// GEMM, Round-6 theory: INTER-BLOCK overlap (m114 mechanism).  All prior
// variants used 128KB LDS -> 1 block/CU -> 8 barrier-locked waves -> MFMA/LDS/
// VALU pipes serialize (MfmaUtil pinned at ~40% across 4 different source
// schedules).  This version: 128x128 tile, BK=64, 256 thr (4 waves 2x2),
// per-wave 64x64 (acc 64 regs), LDS dbuf = 64KB -> __launch_bounds__(256,2)
// -> 2 INDEPENDENT blocks/CU.  When one block sits at its barrier/drain, the
// sibling block's waves issue MFMA/LDS -- overlap without source pipelining.
// Per-tile schedule (ONE barrier per tile):
//   T: { issue 8x GLD16 staging T+1 -> buf[nxt];      (vmcnt, no wait)
//        kk=0: 8 ds_read frags from buf[cur], 16 MFMA;
//        kk=1: 8 ds_read frags, 16 MFMA;
//        __syncthreads() }                            (drains vmcnt+lgkm)
// Safety: stage(T+1->nxt) writes the buffer last READ in tile T-1; those
// ds_reads retired before T-1's closing barrier (lgkmcnt(0) in syncthreads)
// -> no WAR race.  Loads issued at tile top have the whole tile's compute
// (~1000+ cyc) before the end-of-tile drain -> latency fully covered.
// T=31 stages dead data (clamped k=0), drained by final barrier.
// XOR-8 chunk swizzle as before (0 bank conflicts measured).
// XCD swizzle: 2048 blocks %8==0; each XCD owns 16 bm (512KB A-slab L2-hot),
// sweeps 16 bn.
// ===========================================================================

#define GLD16(SRC, DST)                                                        \
  __builtin_amdgcn_global_load_lds(                                            \
      (const __attribute__((address_space(1))) unsigned int*)(SRC),            \
      (__attribute__((address_space(3))) unsigned int*)(DST), 16, 0, 0)

__global__ void __launch_bounds__(256, 2) gemm_kernel(const unsigned short* __restrict__ A,
                                                      const unsigned short* __restrict__ Bm,
                                                      const float* __restrict__ scale,
                                                      const float* __restrict__ bias,
                                                      float* __restrict__ out) {
  __shared__ unsigned short As[2][128 * 64];
  __shared__ unsigned short Bs[2][128 * 64];

  const int tid = threadIdx.x;
  const int bid = blockIdx.x;
  const int xcd = bid & 7;
  const int loc = bid >> 3;               // 0..255
  const int bm  = xcd * 16 + (loc >> 4);  // 0..127
  const int bn  = loc & 15;               // 0..15

  const int lane = tid & 63;
  const int wave = tid >> 6;              // 0..3
  const int wm   = wave >> 1;             // 0..1
  const int wn   = wave & 1;              // 0..1
  const int lrow = lane & 15;
  const int lq   = lane >> 4;

  // staging: thread t = row (t>>3) (0..31, +32 per issue), chunk (t&7);
  // LDS dest linear at t*16 (+4096 per issue); global col pre-swizzled XOR-8.
  const int sr = tid >> 3;
  const int sc = tid & 7;
  const unsigned short* aG = A  + (size_t)(bm * 128 + sr) * IN_DIM + ((sc ^ (sr & 7)) * 8);
  const unsigned short* bG = Bm + (size_t)(bn * 128 + sr) * IN_DIM + ((sc ^ (sr & 7)) * 8);

  // fragment read bases (element offsets into a [128][64] buffer)
  const int aRow = (wm * 64 + lrow) * 64;
  const int bRow = (wn * 64 + lrow) * 64;
  const int c0   = (lq ^ (lrow & 7)) * 8;   // kk=0 chunk; kk=1 chunk = c0^32

  f32x4 acc[4][4] = {};

  // --- prologue: stage tile 0 -> buf0
  {
    char* aD = (char*)&As[0][0] + tid * 16;
    char* bD = (char*)&Bs[0][0] + tid * 16;
    #pragma unroll
    for (int i = 0; i < 4; ++i) {
      GLD16(aG + (size_t)(i * 32) * IN_DIM, aD + i * 4096);
      GLD16(bG + (size_t)(i * 32) * IN_DIM, bD + i * 4096);
    }
  }
  __syncthreads();

  for (int T = 0; T < IN_DIM / 64; ++T) {
    const int cur = T & 1, nxt = cur ^ 1;
    const size_t kN = (size_t)((T < 31) ? (T + 1) * 64 : 0);  // dead at T=31

    // ---- issue staging for T+1 (no wait; drained by end-of-tile barrier)
    {
      char* aD = (char*)&As[nxt][0] + tid * 16;
      char* bD = (char*)&Bs[nxt][0] + tid * 16;
      #pragma unroll
      for (int i = 0; i < 4; ++i) {
        GLD16(aG + kN + (size_t)(i * 32) * IN_DIM, aD + i * 4096);
        GLD16(bG + kN + (size_t)(i * 32) * IN_DIM, bD + i * 4096);
      }
    }

    // ---- compute tile T from buf[cur]
    const unsigned short* Ac = &As[cur][0];
    const unsigned short* Bc = &Bs[cur][0];
    #pragma unroll
    for (int kk = 0; kk < 2; ++kk) {
      const int ck = c0 ^ (kk * 32);
      s16x8 af[4], bf[4];
      #pragma unroll
      for (int mi = 0; mi < 4; ++mi)
        af[mi] = *(const s16x8*)(Ac + aRow + mi * 1024 + ck);
      #pragma unroll
      for (int ni = 0; ni < 4; ++ni)
        bf[ni] = *(const s16x8*)(Bc + bRow + ni * 1024 + ck);
      __builtin_amdgcn_s_setprio(1);
      #pragma unroll
      for (int mi = 0; mi < 4; ++mi)
        #pragma unroll
        for (int ni = 0; ni < 4; ++ni)
          acc[mi][ni] = __builtin_amdgcn_mfma_f32_16x16x32_bf16(af[mi], bf[ni], acc[mi][ni], 0, 0, 0);
      __builtin_amdgcn_s_setprio(0);
    }

    __syncthreads();   // drains vmcnt (T+1 staged) + lgkm; block-local only
  }

  // ---------- epilogue: D lane map col=lane&15, row=(lane>>4)*4 + r
  const int row0 = bm * 128 + wm * 64 + lq * 4;
  const int col0 = bn * 128 + wn * 64 + lrow;
  #pragma unroll
  for (int mi = 0; mi < 4; ++mi) {
    const int row = row0 + mi * 16;
    const f32x4 sc4 = *(const f32x4*)(scale + row);
    #pragma unroll
    for (int ni = 0; ni < 4; ++ni) {
      const int col = col0 + ni * 16;
      const float bcol = bias[col];
      #pragma unroll
      for (int r = 0; r < 4; ++r) {
        float v = acc[mi][ni][r] * sc4[r] + bcol;
        out[(size_t)(row + r) * OUT_DIM + col] = fmaxf(v, 0.0f);
      }
    }
  }
}

extern "C" void kernel_launch(void* const* d_in, const int* in_sizes, int n_in,
                              void* d_out, int out_size, void* d_ws, size_t ws_size,
                              hipStream_t stream) {
  const float* x = (const float*)d_in[0];
  const float* W = (const float*)d_in[1];
  const float* b = (const float*)d_in[2];
  float* out = (float*)d_out;

  char* ws = (char*)d_ws;
  unsigned short* xn    = (unsigned short*)ws;                                  // 67108864 B
  unsigned short* Wb    = (unsigned short*)(ws + (size_t)67108864);             //  8388608 B
  float*          scale = (float*)(ws + (size_t)67108864 + (size_t)8388608);    //    65536 B

  prep_kernel<<<PREP_X_BLOCKS + PREP_W_BLOCKS, 256, 0, stream>>>(x, xn, scale, W, Wb);

  gemm_kernel<<<(OUT_DIM / 128) * (B_ROWS / 128), 256, 0, stream>>>(xn, Wb, scale, b, out);
}

// Round 9
// 375.763 us; speedup vs baseline: 1.0343x; 1.0343x over previous
//
#include <hip/hip_runtime.h>
#include <hip/hip_bf16.h>
#include <stdint.h>

#define B_ROWS 16384
#define IN_DIM 2048
#define OUT_DIM 2048

typedef __attribute__((ext_vector_type(4))) float f32x4;
typedef __attribute__((ext_vector_type(16))) float f32x16;
typedef __attribute__((ext_vector_type(8))) short s16x8;
typedef __attribute__((ext_vector_type(4))) unsigned short u16x4;

__device__ __forceinline__ unsigned short f2bf_rne(float f) {
  union { float f; unsigned u; } c; c.f = f;
  unsigned u = c.u;
  return (unsigned short)((u + 0x7FFFu + ((u >> 16) & 1u)) >> 16);
}

// Prep: measured at its floor (R6 A/B: contiguous vs strided identical). Frozen.
#define PREP_X_BLOCKS 4096
#define PREP_W_BLOCKS 2048

__global__ void __launch_bounds__(256) prep_kernel(const float* __restrict__ x,
                                                   unsigned short* __restrict__ xn,
                                                   float* __restrict__ scale,
                                                   const float* __restrict__ W,
                                                   unsigned short* __restrict__ Wb) {
  if (blockIdx.x < PREP_X_BLOCKS) {
    const int row  = (blockIdx.x * 256 + threadIdx.x) >> 6;
    const int lane = threadIdx.x & 63;
    const f32x4* xr = (const f32x4*)(x + (size_t)row * IN_DIM);
    u16x4* xw = (u16x4*)(xn + (size_t)row * IN_DIM);

    float ss = 0.0f;
    #pragma unroll
    for (int j = 0; j < 8; ++j) {
      const int i = j * 64 + lane;
      f32x4 v = xr[i];
      ss = fmaf(v[0], v[0], ss);
      ss = fmaf(v[1], v[1], ss);
      ss = fmaf(v[2], v[2], ss);
      ss = fmaf(v[3], v[3], ss);
      u16x4 p;
      p[0] = f2bf_rne(v[0]); p[1] = f2bf_rne(v[1]);
      p[2] = f2bf_rne(v[2]); p[3] = f2bf_rne(v[3]);
      xw[i] = p;
    }

    #pragma unroll
    for (int m = 32; m > 0; m >>= 1) ss += __shfl_xor(ss, m, 64);
    if (lane == 0) scale[row] = 1.0f / (sqrtf(ss) + 1e-4f);
  } else {
    const int base = (blockIdx.x - PREP_X_BLOCKS) * 512 + threadIdx.x;
    const f32x4* wr = (const f32x4*)W;
    u16x4* ww = (u16x4*)Wb;
    #pragma unroll
    for (int j = 0; j < 2; ++j) {
      const int i = base + j * 256;
      f32x4 v = wr[i];
      u16x4 p;
      p[0] = f2bf_rne(v[0]); p[1] = f2bf_rne(v[1]);
      p[2] = f2bf_rne(v[2]); p[3] = f2bf_rne(v[3]);
      ww[i] = p;
    }
  }
}

// ===========================================================================
// GEMM: V2 skeleton (best measured: 134.5 us; stages/fences/barriers verified
// over 5 rounds bit-identical) with the MFMA shape swapped 16x16x32 ->
// 32x32x16 (4061 vs 3378 FLOP/cyc/CU, and HALF the MFMA instruction count ->
// frees issue slots for other waves' ds_reads in the serialized-pipe regime).
// 256x256 tile, BK=64, 512 thr (8 waves 2Mx4N), per-wave 128x64 via 4x2 of
// 32x32; acc = f32x16[4][2] (128 regs, same budget as V2).
// MFMA groups (8 mfma each), mirroring V2's read-row structure:
//   G1={mi0,1}x{s0,1}  G2={mi0,1}x{s2,3}  G3={mi2,3}x{s0,1}  G4={mi2,3}x{s2,3}
//   (s = K:16 slice; G1/G2 read A-even quarters, G3/G4 A-odd -- same quarters
//    as V2, so V2's stage/fence ledger carries over verbatim.)
// B-frag reuse: bP (s0,1) read p4, used G1@p1 and G3@p3; bQ (s2,3) read p1,
// used G2@p2 and G4@p4.  A-frags ping-pong aP/aQ.
//   p1: read G2 frags (aQ,bQ: 8 rd) | GLD Ae(T+1) | MFMA G1 | vmcnt(4) bar
//   p2: read G3 frags (aP: 4 rd)    | GLD Bh1(T+1)| MFMA G2
//   p3: read G4 frags (aQ: 4 rd)    | GLD Ao(T+1) | MFMA G3 | vmcnt(2) bar
//   p4: read G1(T+1) (aP,bP of nxt) | GLD Bh0(T+2)->cur | MFMA G4
// Ledger (2 vmcnt slots/stage, re-verified): start-p1 [Ao(T),Bh0(T+1)]=4;
// p1 +Ae(T+1)->6, vmcnt(4) retires Ao(T) (feeds p2/p3 A-odd reads); p2
// +Bh1(T+1)->6; p3 +Ao(T+1)->8, vmcnt(2) retires Bh0/Ae/Bh1(T+1) (feeds p4
// reads of nxt).  Never vmcnt(0) in loop.  32x32x16 frag map: A lane l ->
// row=l&31, k=(l>>5)*8; chunk = (2s+lh)^(l31&7) under the XOR-8 swizzle
// (mi*32 preserves row&7).  D map: col=lane&31, row=(q&3)+8*(q>>2)+4*lh.
// WATCH: SQ_LDS_BANK_CONFLICT (new read pattern) and VGPR spill.
// ===========================================================================

#define GLD16(SRC, DST)                                                        \
  __builtin_amdgcn_global_load_lds(                                            \
      (const __attribute__((address_space(1))) unsigned int*)(SRC),            \
      (__attribute__((address_space(3))) unsigned int*)(DST), 16, 0, 0)

__global__ void __launch_bounds__(512, 1) gemm_kernel(const unsigned short* __restrict__ A,
                                                      const unsigned short* __restrict__ Bm,
                                                      const float* __restrict__ scale,
                                                      const float* __restrict__ bias,
                                                      float* __restrict__ out) {
  __shared__ unsigned short As[2][256 * 64];
  __shared__ unsigned short Bs[2][256 * 64];

  const int tid = threadIdx.x;
  const int bid = blockIdx.x;
  const int xcd = bid & 7;
  const int loc = bid >> 3;               // 0..63
  const int bm  = xcd * 8 + (loc >> 3);   // 0..63
  const int bn  = loc & 7;                // 0..7

  const int lane = tid & 63;
  const int wave = tid >> 6;              // 0..7
  const int wm   = wave >> 2;             // 0..1
  const int wn   = wave & 3;              // 0..3
  const int l31  = lane & 31;
  const int lh   = lane >> 5;

  // staging: thread t = row (t>>3), chunk (t&7); LDS dest linear at t*16;
  // global col pre-swizzled (XOR-8).  Identical to V2.
  const int sr = tid >> 3;
  const int sc = tid & 7;
  const unsigned short* aG = A  + (size_t)(bm * 256 + sr) * IN_DIM + ((sc ^ (sr & 7)) * 8);
  const unsigned short* bG = Bm + (size_t)(bn * 256 + sr) * IN_DIM + ((sc ^ (sr & 7)) * 8);

  // fragment read bases (element offsets into a [256][64] buffer)
  const int aRowBase = (wm * 128 + l31) * 64;   // + mi*2048 + ck[s]
  const int bRowBase = (wn * 64  + l31) * 64;   // + ni*2048 + ck[s]
  int ck[4];
  #pragma unroll
  for (int s = 0; s < 4; ++s) ck[s] = ((2 * s + lh) ^ (l31 & 7)) * 8;

  f32x16 acc[4][2] = {};
  s16x8 aP[2][2], aQ[2][2];   // [mi-in-pair][s-in-pair]
  s16x8 bP[2][2], bQ[2][2];   // [ni][s-in-pair]: bP = s0,1; bQ = s2,3

  // --- prologue: stage tile 0 (B-h0,B-h1,A-even,A-odd) + B-h0(1)  [V2-exact]
  {
    char* aD = (char*)&As[0][0] + tid * 16;
    char* bD = (char*)&Bs[0][0] + tid * 16;
    char* bD1 = (char*)&Bs[1][0] + tid * 16;
    GLD16(bG,                         bD);           // B-h0(0): rows 0-127
    GLD16(bG + (size_t) 64 * IN_DIM,  bD + 8192);
    GLD16(bG + (size_t)128 * IN_DIM,  bD + 16384);   // B-h1(0): rows 128-255
    GLD16(bG + (size_t)192 * IN_DIM,  bD + 24576);
    GLD16(aG,                         aD);           // A-even(0): rows 0-63,128-191
    GLD16(aG + (size_t)128 * IN_DIM,  aD + 16384);
    GLD16(aG + (size_t) 64 * IN_DIM,  aD + 8192);    // A-odd(0): rows 64-127,192-255
    GLD16(aG + (size_t)192 * IN_DIM,  aD + 24576);
    GLD16(bG + 64,                        bD1);      // B-h0(1)
    GLD16(bG + 64 + (size_t)64 * IN_DIM,  bD1 + 8192);
  }
  asm volatile("s_waitcnt vmcnt(4)" ::: "memory");  // Bh0(0),Bh1(0),Ae(0) landed
  __builtin_amdgcn_s_barrier();

  // G1(0) frags: aP <- A mi{0,1} s{0,1}; bP <- B ni{0,1} s{0,1}  (buf0)
  #pragma unroll
  for (int mi = 0; mi < 2; ++mi)
    #pragma unroll
    for (int s = 0; s < 2; ++s)
      aP[mi][s] = *(const s16x8*)(&As[0][aRowBase + mi * 2048 + ck[s]]);
  #pragma unroll
  for (int ni = 0; ni < 2; ++ni)
    #pragma unroll
    for (int s = 0; s < 2; ++s)
      bP[ni][s] = *(const s16x8*)(&Bs[0][bRowBase + ni * 2048 + ck[s]]);

  for (int T = 0; T < IN_DIM / 64; ++T) {
    const int cur = T & 1, nxt = cur ^ 1;
    const unsigned short* Ac = &As[cur][0];
    const unsigned short* Bc = &Bs[cur][0];
    const unsigned short* An = &As[nxt][0];
    const unsigned short* Bn = &Bs[nxt][0];
    char* aD  = (char*)&As[nxt][0] + tid * 16;
    char* bD  = (char*)&Bs[nxt][0] + tid * 16;
    char* bDc = (char*)&Bs[cur][0] + tid * 16;
    const size_t k1 = (size_t)((T < 31) ? (T + 1) * 64 : 0);
    const size_t k2 = (size_t)((T < 30) ? (T + 2) * 64 : 0);

    // ---- p1: read G2 (aQ: mi01 s23, bQ: ni01 s23) | GLD Ae(T+1) | MFMA G1 | vmcnt(4) bar
    #pragma unroll
    for (int mi = 0; mi < 2; ++mi)
      #pragma unroll
      for (int s = 0; s < 2; ++s)
        aQ[mi][s] = *(const s16x8*)(Ac + aRowBase + mi * 2048 + ck[2 + s]);
    #pragma unroll
    for (int ni = 0; ni < 2; ++ni)
      #pragma unroll
      for (int s = 0; s < 2; ++s)
        bQ[ni][s] = *(const s16x8*)(Bc + bRowBase + ni * 2048 + ck[2 + s]);
    GLD16(aG + k1,                         aD);
    GLD16(aG + k1 + (size_t)128 * IN_DIM,  aD + 16384);
    __builtin_amdgcn_s_setprio(1);
    #pragma unroll
    for (int s = 0; s < 2; ++s)
      #pragma unroll
      for (int mi = 0; mi < 2; ++mi)
        #pragma unroll
        for (int ni = 0; ni < 2; ++ni)
          acc[mi][ni] = __builtin_amdgcn_mfma_f32_32x32x16_bf16(aP[mi][s], bP[ni][s], acc[mi][ni], 0, 0, 0);
    __builtin_amdgcn_s_setprio(0);
    asm volatile("s_waitcnt vmcnt(4)" ::: "memory");  // A-odd(T) landed
    __builtin_amdgcn_s_barrier();

    // ---- p2: read G3 (aP: mi23 s01) | GLD Bh1(T+1) | MFMA G2
    #pragma unroll
    for (int mi = 0; mi < 2; ++mi)
      #pragma unroll
      for (int s = 0; s < 2; ++s)
        aP[mi][s] = *(const s16x8*)(Ac + aRowBase + (2 + mi) * 2048 + ck[s]);
    GLD16(bG + k1 + (size_t)128 * IN_DIM,  bD + 16384);
    GLD16(bG + k1 + (size_t)192 * IN_DIM,  bD + 24576);
    __builtin_amdgcn_s_setprio(1);
    #pragma unroll
    for (int s = 0; s < 2; ++s)
      #pragma unroll
      for (int mi = 0; mi < 2; ++mi)
        #pragma unroll
        for (int ni = 0; ni < 2; ++ni)
          acc[mi][ni] = __builtin_amdgcn_mfma_f32_32x32x16_bf16(aQ[mi][s], bQ[ni][s], acc[mi][ni], 0, 0, 0);
    __builtin_amdgcn_s_setprio(0);

    // ---- p3: read G4 (aQ: mi23 s23) | GLD Ao(T+1) | MFMA G3 | vmcnt(2) bar
    #pragma unroll
    for (int mi = 0; mi < 2; ++mi)
      #pragma unroll
      for (int s = 0; s < 2; ++s)
        aQ[mi][s] = *(const s16x8*)(Ac + aRowBase + (2 + mi) * 2048 + ck[2 + s]);
    GLD16(aG + k1 + (size_t) 64 * IN_DIM,  aD + 8192);
    GLD16(aG + k1 + (size_t)192 * IN_DIM,  aD + 24576);
    __builtin_amdgcn_s_setprio(1);
    #pragma unroll
    for (int s = 0; s < 2; ++s)
      #pragma unroll
      for (int mi = 0; mi < 2; ++mi)
        #pragma unroll
        for (int ni = 0; ni < 2; ++ni)
          acc[2 + mi][ni] = __builtin_amdgcn_mfma_f32_32x32x16_bf16(aP[mi][s], bP[ni][s], acc[2 + mi][ni], 0, 0, 0);
    __builtin_amdgcn_s_setprio(0);
    asm volatile("s_waitcnt vmcnt(2)" ::: "memory");  // Bh0,Ae,Bh1(T+1) landed
    __builtin_amdgcn_s_barrier();

    // ---- p4: read G1(T+1) (aP,bP from nxt) | GLD Bh0(T+2)->cur | MFMA G4
    #pragma unroll
    for (int mi = 0; mi < 2; ++mi)
      #pragma unroll
      for (int s = 0; s < 2; ++s)
        aP[mi][s] = *(const s16x8*)(An + aRowBase + mi * 2048 + ck[s]);
    #pragma unroll
    for (int ni = 0; ni < 2; ++ni)
      #pragma unroll
      for (int s = 0; s < 2; ++s)
        bP[ni][s] = *(const s16x8*)(Bn + bRowBase + ni * 2048 + ck[s]);
    GLD16(bG + k2,                         bDc);
    GLD16(bG + k2 + (size_t) 64 * IN_DIM,  bDc + 8192);
    __builtin_amdgcn_s_setprio(1);
    #pragma unroll
    for (int s = 0; s < 2; ++s)
      #pragma unroll
      for (int mi = 0; mi < 2; ++mi)
        #pragma unroll
        for (int ni = 0; ni < 2; ++ni)
          acc[2 + mi][ni] = __builtin_amdgcn_mfma_f32_32x32x16_bf16(aQ[mi][s], bQ[ni][s], acc[2 + mi][ni], 0, 0, 0);
    __builtin_amdgcn_s_setprio(0);
  }

  // drain dead tail prefetches before exit
  asm volatile("s_waitcnt vmcnt(0)" ::: "memory");

  // ---------- epilogue: 32x32 D map: col=lane&31, row=(q&3)+8*(q>>2)+4*lh
  const int row0 = bm * 256 + wm * 128 + lh * 4;
  const int col0 = bn * 256 + wn * 64 + l31;
  #pragma unroll
  for (int mi = 0; mi < 4; ++mi) {
    #pragma unroll
    for (int ni = 0; ni < 2; ++ni) {
      const int col = col0 + ni * 32;
      const float bcol = bias[col];
      #pragma unroll
      for (int g = 0; g < 4; ++g) {
        const int rb = row0 + mi * 32 + g * 8;
        const f32x4 sc4 = *(const f32x4*)(scale + rb);
        #pragma unroll
        for (int r = 0; r < 4; ++r) {
          float v = acc[mi][ni][g * 4 + r] * sc4[r] + bcol;
          out[(size_t)(rb + r) * OUT_DIM + col] = fmaxf(v, 0.0f);
        }
      }
    }
  }
}

extern "C" void kernel_launch(void* const* d_in, const int* in_sizes, int n_in,
                              void* d_out, int out_size, void* d_ws, size_t ws_size,
                              hipStream_t stream) {
  const float* x = (const float*)d_in[0];
  const float* W = (const float*)d_in[1];
  const float* b = (const float*)d_in[2];
  float* out = (float*)d_out;

  char* ws = (char*)d_ws;
  unsigned short* xn    = (unsigned short*)ws;                                  // 67108864 B
  unsigned short* Wb    = (unsigned short*)(ws + (size_t)67108864);             //  8388608 B
  float*          scale = (float*)(ws + (size_t)67108864 + (size_t)8388608);    //    65536 B

  prep_kernel<<<PREP_X_BLOCKS + PREP_W_BLOCKS, 256, 0, stream>>>(x, xn, scale, W, Wb);

  gemm_kernel<<<(OUT_DIM / 256) * (B_ROWS / 256), 512, 0, stream>>>(xn, Wb, scale, b, out);
}